// Round 3
// baseline (296.888 us; speedup 1.0000x reference)
//
#include <hip/hip_runtime.h>

// Problem constants (fixed by setup_inputs)
static constexpr int V  = 5;
static constexpr int B  = 2;
static constexpr int C  = 32;
static constexpr int H  = 256;
static constexpr int W  = 320;
static constexpr int CN = 4;
static constexpr int HW = H * W;
static constexpr int CG = 8;   // channels per group (per wave)
static constexpr int NG = 4;   // groups per block
static constexpr int XT = W / 64;        // 5 x-tiles
static constexpr int NBLK = XT * H * B;  // 2560 fused blocks

// ws layout: params only now (96 floats)
static constexpr size_t PARAMS_OFF = 0;

typedef float f32x2 __attribute__((ext_vector_type(2)));
typedef float f32x4 __attribute__((ext_vector_type(4)));

// Alignment-safe paired load (backend emits unaligned-capable dwordx2)
__device__ __forceinline__ f32x2 ld2(const float* p) {
    f32x2 v;
    __builtin_memcpy(&v, p, sizeof(f32x2));
    return v;
}

// ---------------------------------------------------------------------------
// Setup: per (b, src view i=1..4) compute proj = M_i @ inv(M_0) -> 12 floats
// ---------------------------------------------------------------------------
__global__ void setup_proj_kernel(const float* __restrict__ pm, float* __restrict__ params) {
    int b = threadIdx.x;
    if (b >= B) return;

    float M[V][16];
    for (int v = 0; v < V; ++v) {
        const float* E  = pm + ((size_t)(b * V + v) * 2 + 0) * 16;
        const float* Km = pm + ((size_t)(b * V + v) * 2 + 1) * 16;
        for (int r = 0; r < 3; ++r)
            for (int c = 0; c < 4; ++c) {
                float s = 0.f;
                for (int k = 0; k < 3; ++k) s += Km[r * 4 + k] * E[k * 4 + c];
                M[v][r * 4 + c] = s;
            }
        for (int c = 0; c < 4; ++c) M[v][12 + c] = E[12 + c];
    }

    float A[9], bb[3];
    for (int r = 0; r < 3; ++r) {
        for (int c = 0; c < 3; ++c) A[r * 3 + c] = M[0][r * 4 + c];
        bb[r] = M[0][r * 4 + 3];
    }
    float det = A[0] * (A[4] * A[8] - A[5] * A[7])
              - A[1] * (A[3] * A[8] - A[5] * A[6])
              + A[2] * (A[3] * A[7] - A[4] * A[6]);
    float id = 1.f / det;
    float Ai[9];
    Ai[0] = (A[4] * A[8] - A[5] * A[7]) * id;
    Ai[1] = (A[2] * A[7] - A[1] * A[8]) * id;
    Ai[2] = (A[1] * A[5] - A[2] * A[4]) * id;
    Ai[3] = (A[5] * A[6] - A[3] * A[8]) * id;
    Ai[4] = (A[0] * A[8] - A[2] * A[6]) * id;
    Ai[5] = (A[2] * A[3] - A[0] * A[5]) * id;
    Ai[6] = (A[3] * A[7] - A[4] * A[6]) * id;
    Ai[7] = (A[1] * A[6] - A[0] * A[7]) * id;
    Ai[8] = (A[0] * A[4] - A[1] * A[3]) * id;
    float bi[3];
    for (int r = 0; r < 3; ++r)
        bi[r] = -(Ai[r * 3 + 0] * bb[0] + Ai[r * 3 + 1] * bb[1] + Ai[r * 3 + 2] * bb[2]);

    float Minv[16];
    for (int r = 0; r < 3; ++r) {
        for (int c = 0; c < 3; ++c) Minv[r * 4 + c] = Ai[r * 3 + c];
        Minv[r * 4 + 3] = bi[r];
    }
    Minv[12] = 0.f; Minv[13] = 0.f; Minv[14] = 0.f; Minv[15] = 1.f;

    for (int v = 1; v < V; ++v) {
        float* dst = params + (size_t)(b * (V - 1) + (v - 1)) * 12;
        for (int r = 0; r < 3; ++r)
            for (int c = 0; c < 4; ++c) {
                float s = 0.f;
                for (int k = 0; k < 4; ++k) s += M[v][r * 4 + k] * Minv[k * 4 + c];
                dst[r * 4 + c] = s;
            }
    }
}

// ---------------------------------------------------------------------------
// Fused kernel: one block per (b, y, x-tile). Block = 64 px x 4 ch-groups.
// Each thread accumulates volsum[k] over ALL 4 source views, LDS-reduces
// across channel groups, normalizes by locally-computed wsum, then the block
// broadcast-writes the 128 output planes with regular cached stores.
//
// v3: wave-uniform second-row skip. If, for every lane and every depth, the
// row-1 bilinear weights are exactly zero (true whenever the projected gy is
// integral — e.g. pure-x-translation rigs — or row 1 is out of range), the
// row-1 loads and FMAs are skipped for the whole wave. Generic data falls
// back to the full 4-corner path; this dataset takes the fast path for every
// wave, halving VMEM instruction count (256 -> 128 ld2/thread).
// ---------------------------------------------------------------------------
__global__ __launch_bounds__(256) void fused_kernel(
    const float* __restrict__ depth_values,   // (B,1,H,W)
    const float* __restrict__ features,       // (V,B,C,H,W)
    const float* __restrict__ depth_interval, // (B,1,H,W)
    const float* __restrict__ view_weights,   // (B,V-1,H,W)
    const float* __restrict__ params,         // (B,V-1,12)
    float* __restrict__ out)                  // (B,C*CN,H,W)
{
    const int tid = threadIdx.x;
    const int p   = tid & 63;
    const int g   = tid >> 6;

    // bijective XCD swizzle: NBLK % 8 == 0, chunk = 320
    const int d  = blockIdx.x;
    const int l  = (d & 7) * (NBLK / 8) + (d >> 3);
    const int xt = l % XT;
    const int r2 = l / XT;          // 0..511
    const int y  = r2 & (H - 1);
    const int b  = r2 >> 8;

    const int x   = xt * 64 + p;
    const int pix = y * W + x;

    __shared__ float sp4[48];                // 4 views x 12 params
    __shared__ float sred[NG][CN][64];       // cross-group reduce
    __shared__ float sim_lds[CN][64];        // normalized sim for store phase
    if (tid < 48) sp4[tid] = params[(size_t)b * 48 + tid];
    __syncthreads();

    const float invd = 1.f / depth_values[(size_t)b * HW + pix];
    const float itv  = depth_interval[(size_t)b * HW + pix];
    const float low  = invd - (CN * 0.5f) * itv;
    const float step = (CN * itv) / (float)(CN - 1);
    float dep[CN];
#pragma unroll
    for (int k = 0; k < CN; ++k) dep[k] = 1.f / (low + (float)k * step);

    // this group's reference channels: read exactly once globally -> NT load
    const float* refp = features + ((size_t)b * C + g * CG) * HW + pix;
    float rf[CG];
#pragma unroll
    for (int c = 0; c < CG; ++c) rf[c] = __builtin_nontemporal_load(refp + (size_t)c * HW);

    const float fx = (float)x, fy = (float)y;

    float volsum[CN] = {0.f, 0.f, 0.f, 0.f};
    float wsum = 1e-5f;

    for (int iv = 0; iv < V - 1; ++iv) {
        const float* spv = &sp4[iv * 12];
        const float rx = spv[0] * fx + spv[1] * fy + spv[2];
        const float ry = spv[4] * fx + spv[5] * fy + spv[6];
        const float rz = spv[8] * fx + spv[9] * fy + spv[10];
        const float tx = spv[3], ty = spv[7], tz = spv[11];

        const float vw = view_weights[((size_t)b * (V - 1) + iv) * HW + pix];
        wsum += vw;
        const float scale = vw * (1.f / (float)C);

        const float* src = features + ((size_t)((iv + 1) * B + b) * C + g * CG) * HW;

        int   ib0[CN], ib1[CN];
        float wA0[CN], wB0[CN], wA1[CN], wB1[CN];
#pragma unroll
        for (int k = 0; k < CN; ++k) {
            const float dd = dep[k];
            const float px = rx * dd + tx;
            const float py = ry * dd + ty;
            const float pz = rz * dd + tz;
            const float iz = 1.f / pz;
            const float gx = px * iz;
            const float gy = py * iz;

            const float x0f = floorf(gx), y0f = floorf(gy);
            const float wx1 = gx - x0f, wy1 = gy - y0f;
            const float wx0 = 1.f - wx1, wy0 = 1.f - wy1;
            const int x0 = (int)x0f, y0 = (int)y0f;
            const int x1 = x0 + 1, y1 = y0 + 1;

            const bool vx0 = (x0 >= 0) && (x0 <= W - 1);
            const bool vx1 = (x1 >= 0) && (x1 <= W - 1);
            const bool vy0 = (y0 >= 0) && (y0 <= H - 1);
            const bool vy1 = (y1 >= 0) && (y1 <= H - 1);

            const int cy0 = min(max(y0, 0), H - 1);
            const int cy1 = min(max(y1, 0), H - 1);
            const int bx  = min(max(x0, 0), W - 2);
            const int s   = x0 - bx;   // {-1, 0, 1} (else all weights 0)

            const float w00 = wx0 * wy0 * ((vx0 && vy0) ? scale : 0.f);
            const float w10 = wx1 * wy0 * ((vx1 && vy0) ? scale : 0.f);
            const float w01 = wx0 * wy1 * ((vx0 && vy1) ? scale : 0.f);
            const float w11 = wx1 * wy1 * ((vx1 && vy1) ? scale : 0.f);

            wA0[k] = (s == 0) ? w00 : ((s == -1) ? w10 : 0.f);
            wB0[k] = (s == 0) ? w10 : ((s == 1) ? w00 : 0.f);
            wA1[k] = (s == 0) ? w01 : ((s == -1) ? w11 : 0.f);
            wB1[k] = (s == 0) ? w11 : ((s == 1) ? w01 : 0.f);

            ib0[k] = cy0 * W + bx;
            ib1[k] = cy1 * W + bx;
        }

        // wave-uniform fast path: row 1 contributes nothing for any lane/depth
        bool skip1 = true;
#pragma unroll
        for (int k = 0; k < CN; ++k)
            skip1 = skip1 && (wA1[k] == 0.f) && (wB1[k] == 0.f);

        if (__all(skip1)) {
            // row-0-only gather: 32 ld2 per view (vs 64)
#pragma unroll
            for (int cc = 0; cc < CG; cc += 4) {
                f32x2 P0[4][CN];
#pragma unroll
                for (int c = 0; c < 4; ++c) {
                    const float* fc = src + (size_t)(cc + c) * HW;
#pragma unroll
                    for (int k = 0; k < CN; ++k)
                        P0[c][k] = ld2(fc + ib0[k]);
                }
#pragma unroll
                for (int c = 0; c < 4; ++c) {
                    const float rfc = rf[cc + c];
#pragma unroll
                    for (int k = 0; k < CN; ++k) {
                        float t = wA0[k] * P0[c][k].x;
                        t = fmaf(wB0[k], P0[c][k].y, t);
                        volsum[k] = fmaf(rfc, t, volsum[k]);
                    }
                }
            }
        } else {
            // full 4-corner path (generic data)
#pragma unroll
            for (int cc = 0; cc < CG; cc += 4) {
                f32x2 P0[4][CN], P1[4][CN];
#pragma unroll
                for (int c = 0; c < 4; ++c) {
                    const float* fc = src + (size_t)(cc + c) * HW;
#pragma unroll
                    for (int k = 0; k < CN; ++k) {
                        P0[c][k] = ld2(fc + ib0[k]);
                        P1[c][k] = ld2(fc + ib1[k]);
                    }
                }
#pragma unroll
                for (int c = 0; c < 4; ++c) {
                    const float rfc = rf[cc + c];
#pragma unroll
                    for (int k = 0; k < CN; ++k) {
                        float t = wA0[k] * P0[c][k].x;
                        t = fmaf(wB0[k], P0[c][k].y, t);
                        t = fmaf(wA1[k], P1[c][k].x, t);
                        t = fmaf(wB1[k], P1[c][k].y, t);
                        volsum[k] = fmaf(rfc, t, volsum[k]);
                    }
                }
            }
        }
    }

    // cross-group reduce + normalize (NG == CN: group g owns depth k = g)
#pragma unroll
    for (int k = 0; k < CN; ++k) sred[g][k][p] = volsum[k];
    __syncthreads();

    {
        const int k = g;
        const float s = sred[0][k][p] + sred[1][k][p] + sred[2][k][p] + sred[3][k][p];
        sim_lds[k][p] = s * (1.f / wsum);   // every thread has wsum for its px
    }
    __syncthreads();

    // broadcast-write 128 planes x 64 px (32 KB) with regular cached stores.
    // thread: quad = tid&15 (4-px f32x4), pc = tid>>4; 8 planes per thread.
    {
        const int quad = tid & 15;
        const int pc   = tid >> 4;
        float* op = out + (size_t)b * C * CN * HW + y * W + xt * 64 + quad * 4;
#pragma unroll
        for (int j = 0; j < 8; ++j) {
            const int plane = pc * 8 + j;          // 0..127, each exactly once
            const int k     = plane & 3;           // == j & 3
            const f32x4 v   = *(const f32x4*)&sim_lds[k][quad * 4];
            *(f32x4*)(op + (size_t)plane * HW) = v;
        }
    }
}

extern "C" void kernel_launch(void* const* d_in, const int* in_sizes, int n_in,
                              void* d_out, int out_size, void* d_ws, size_t ws_size,
                              hipStream_t stream) {
    const float* depth_values   = (const float*)d_in[0];
    const float* features       = (const float*)d_in[1];
    const float* proj_matrices  = (const float*)d_in[2];
    const float* depth_interval = (const float*)d_in[3];
    const float* view_weights   = (const float*)d_in[7];
    float* out    = (float*)d_out;
    float* params = (float*)d_ws + PARAMS_OFF;    // 96 floats

    setup_proj_kernel<<<1, B, 0, stream>>>(proj_matrices, params);

    fused_kernel<<<NBLK, 256, 0, stream>>>(depth_values, features, depth_interval,
                                           view_weights, params, out);
}